// Round 1
// baseline (344.112 us; speedup 1.0000x reference)
//
#include <hip/hip_runtime.h>
#include <hip/hip_bf16.h>
#include <cstdint>
#include <cstddef>

// ---- problem constants ----
#define BATCH 2
#define SEQ   2048
#define DM    1024
#define NH    16
#define DK    64
#define MROWS (BATCH*SEQ)   // 4096

typedef __bf16 bf16;
typedef float  f32x4  __attribute__((ext_vector_type(4)));
typedef bf16   bf16x8 __attribute__((ext_vector_type(8)));
typedef bf16   bf16x4 __attribute__((ext_vector_type(4)));

#define MFMA16(a, b, c) __builtin_amdgcn_mfma_f32_16x16x32_bf16(a, b, c, 0, 0, 0)

// async global->LDS, 16B per lane; LDS dest is wave-uniform base + lane*16
__device__ __forceinline__ void llds16(const void* gc, void* l) {
    void* g = (void*)gc;  // drop const
    __builtin_amdgcn_global_load_lds(
        (__attribute__((address_space(1))) uint32_t*)g,
        (__attribute__((address_space(3))) uint32_t*)l,
        16, 0, 0);
}

// ---------------- fused fp32 -> bf16 convert (q,k,v + 4 weights) ----------------
__global__ __launch_bounds__(256) void k_convert(
    const float* __restrict__ q, const float* __restrict__ k, const float* __restrict__ v,
    const float* __restrict__ wq, const float* __restrict__ wk, const float* __restrict__ wv,
    const float* __restrict__ wo,
    bf16* __restrict__ qb, bf16* __restrict__ kb, bf16* __restrict__ vb,
    bf16* __restrict__ wqb, bf16* __restrict__ wkb, bf16* __restrict__ wvb,
    bf16* __restrict__ wob) {
    long t = (long)blockIdx.x * blockDim.x + threadIdx.x;   // one float4 per thread
    const long NQ = (long)MROWS * DM / 4;                   // 1,048,576 vec4 per activation
    const long NW = (long)DM * DM / 4;                      // 262,144 vec4 per weight
    const float* src; bf16* dst; long off;
    if (t < NQ)            { src = q;  dst = qb;  off = t; }
    else if (t < 2*NQ)     { src = k;  dst = kb;  off = t - NQ; }
    else if (t < 3*NQ)     { src = v;  dst = vb;  off = t - 2*NQ; }
    else {
        long u = t - 3*NQ;
        if (u < NW)        { src = wq; dst = wqb; off = u; }
        else if (u < 2*NW) { src = wk; dst = wkb; off = u - NW; }
        else if (u < 3*NW) { src = wv; dst = wvb; off = u - 2*NW; }
        else               { src = wo; dst = wob; off = u - 3*NW; }
    }
    f32x4 x = *(const f32x4*)(src + off * 4);
    bf16x4 y;
    y[0] = (bf16)x[0]; y[1] = (bf16)x[1]; y[2] = (bf16)x[2]; y[3] = (bf16)x[3];
    *(bf16x4*)(dst + off * 4) = y;
}

// ---------------- m97-style GEMM: C[M,N] = A[M,K] * W[N,K]^T + bias ----------------
// 128x128 tile, BK=32, 4 waves in 2x2, each wave 64x64 as 4x4 of 16x16x32 MFMA.
template <typename OutT>
__device__ __forceinline__ void gemm128(const bf16* __restrict__ A, const bf16* __restrict__ W,
                                        const float* __restrict__ bias, OutT* __restrict__ C,
                                        int m0, int n0) {
    constexpr int K = DM, N = DM, BK = 32;
    __shared__ bf16 sA[128 * BK];
    __shared__ bf16 sB[128 * BK];
    const int tid = threadIdx.x;
    const int l = tid & 63, w = tid >> 6;
    const int quad = l >> 4, l15 = l & 15;
    const int wm = w & 1, wn = w >> 1;

    f32x4 acc[4][4] = {};

    for (int k0 = 0; k0 < K; k0 += BK) {
        // stage A[128xBK], B[128xBK]; each wave: 2 issues of 16 rows per matrix
#pragma unroll
        for (int i = 0; i < 2; ++i) {
            int r16 = w * 32 + i * 16;
            const bf16* ga = A + (size_t)(m0 + r16 + (l >> 2)) * K + k0 + (l & 3) * 8;
            const bf16* gb = W + (size_t)(n0 + r16 + (l >> 2)) * K + k0 + (l & 3) * 8;
            llds16(ga, &sA[r16 * BK]);
            llds16(gb, &sB[r16 * BK]);
        }
        __syncthreads();

        bf16x8 af[4], bfr[4];
#pragma unroll
        for (int mi = 0; mi < 4; ++mi)
            af[mi] = *(const bf16x8*)&sA[(wm * 64 + mi * 16 + l15) * BK + quad * 8];
#pragma unroll
        for (int ni = 0; ni < 4; ++ni)
            bfr[ni] = *(const bf16x8*)&sB[(wn * 64 + ni * 16 + l15) * BK + quad * 8];
#pragma unroll
        for (int mi = 0; mi < 4; ++mi)
#pragma unroll
            for (int ni = 0; ni < 4; ++ni)
                acc[mi][ni] = MFMA16(af[mi], bfr[ni], acc[mi][ni]);
        __syncthreads();
    }

    // epilogue: C/D layout col=lane&15, row=quad*4+reg
#pragma unroll
    for (int mi = 0; mi < 4; ++mi) {
#pragma unroll
        for (int ni = 0; ni < 4; ++ni) {
            int col = n0 + wn * 64 + ni * 16 + l15;
            float bv = bias[col];
            int rbase = m0 + wm * 64 + mi * 16 + quad * 4;
#pragma unroll
            for (int r = 0; r < 4; ++r) {
                float val = acc[mi][ni][r] + bv;
                C[(size_t)(rbase + r) * N + col] = (OutT)val;
            }
        }
    }
}

__global__ __launch_bounds__(256) void k_gemm_qkv(
    const bf16* __restrict__ qb, const bf16* __restrict__ kb, const bf16* __restrict__ vb,
    const bf16* __restrict__ wqb, const bf16* __restrict__ wkb, const bf16* __restrict__ wvb,
    const float* __restrict__ bq, const float* __restrict__ bk, const float* __restrict__ bv,
    bf16* __restrict__ Qp, bf16* __restrict__ Kp, bf16* __restrict__ Vp) {
    int z = blockIdx.z;
    const bf16* A = (z == 0) ? qb : (z == 1) ? kb : vb;
    const bf16* W = (z == 0) ? wqb : (z == 1) ? wkb : wvb;
    const float* bi = (z == 0) ? bq : (z == 1) ? bk : bv;
    bf16* C = (z == 0) ? Qp : (z == 1) ? Kp : Vp;
    gemm128<bf16>(A, W, bi, C, blockIdx.y * 128, blockIdx.x * 128);
}

__global__ __launch_bounds__(256) void k_gemm_out(
    const bf16* __restrict__ X, const bf16* __restrict__ wob,
    const float* __restrict__ bo, float* __restrict__ out) {
    gemm128<float>(X, wob, bo, out, blockIdx.y * 128, blockIdx.x * 128);
}

// ---------------- V transpose per head: Vt[b][h][d][s] = Vp[b][s][h*64+d] ----------------
__global__ __launch_bounds__(256) void k_transpose_v(const bf16* __restrict__ Vp,
                                                     bf16* __restrict__ Vt) {
    const int b = blockIdx.z, h = blockIdx.y, s0 = blockIdx.x * 64;
    __shared__ bf16 t[64 * 65];
    const int tid = threadIdx.x;
    const int r8 = tid >> 3, c8 = (tid & 7) * 8;
#pragma unroll
    for (int i = 0; i < 2; ++i) {
        int s = i * 32 + r8;
        bf16x8 v = *(const bf16x8*)(Vp + (size_t)(b * SEQ + s0 + s) * DM + h * DK + c8);
#pragma unroll
        for (int j = 0; j < 8; ++j) t[s * 65 + c8 + j] = v[j];
    }
    __syncthreads();
#pragma unroll
    for (int i = 0; i < 2; ++i) {
        int d = i * 32 + r8;
        bf16x8 v;
#pragma unroll
        for (int j = 0; j < 8; ++j) v[j] = t[(c8 + j) * 65 + d];
        *(bf16x8*)(Vt + ((size_t)(b * NH + h) * DK + d) * SEQ + s0 + c8) = v;
    }
}

// ---------------- causal flash attention ----------------
// grid (S/128, B*H); 4 waves, wave owns 32 Q rows. KV tile = 128.
// Q/K frags direct global->reg; V frags direct from transposed Vt; P via wave-private LDS.
__global__ __launch_bounds__(256) void k_flash(const bf16* __restrict__ Qp,
                                               const bf16* __restrict__ Kp,
                                               const bf16* __restrict__ Vt,
                                               bf16* __restrict__ X) {
    const int qt = blockIdx.x;       // Q tile index
    const int bh = blockIdx.y;
    const int b = bh >> 4, h = bh & 15;
    __shared__ bf16 P[128 * 136];    // stride 136: 16B-aligned rows, 2-way-free banks
    const int tid = threadIdx.x, l = tid & 63, w = tid >> 6;
    const int quad = l >> 4, l15 = l & 15;

    const size_t qk_base = (size_t)b * SEQ * DM + h * DK;
    const size_t vt_base = (size_t)(b * NH + h) * DK * SEQ;
    bf16* Pw = &P[(w * 32) * 136];   // wave-private region

    // persistent Q fragments: rows w*32 + mi*16 + l15, k = kk*32 + quad*8
    bf16x8 qf[2][2];
#pragma unroll
    for (int mi = 0; mi < 2; ++mi)
#pragma unroll
        for (int kk = 0; kk < 2; ++kk)
            qf[mi][kk] = *(const bf16x8*)(Qp + qk_base +
                (size_t)(qt * 128 + w * 32 + mi * 16 + l15) * DM + kk * 32 + quad * 8);

    float mstate[2][4], lstate[2][4];
#pragma unroll
    for (int mi = 0; mi < 2; ++mi)
#pragma unroll
        for (int r = 0; r < 4; ++r) { mstate[mi][r] = -1e30f; lstate[mi][r] = 0.f; }
    f32x4 of[2][4] = {};

    for (int j = 0; j <= qt; ++j) {
        // ---- S = Q K^T (per wave: 32 x 128) ----
        f32x4 sa[2][8] = {};
#pragma unroll
        for (int ni = 0; ni < 8; ++ni) {
            const bf16* kr = Kp + qk_base + (size_t)(j * 128 + ni * 16 + l15) * DM + quad * 8;
            bf16x8 kf0 = *(const bf16x8*)(kr);
            bf16x8 kf1 = *(const bf16x8*)(kr + 32);
#pragma unroll
            for (int mi = 0; mi < 2; ++mi) {
                sa[mi][ni] = MFMA16(qf[mi][0], kf0, sa[mi][ni]);
                sa[mi][ni] = MFMA16(qf[mi][1], kf1, sa[mi][ni]);
            }
        }
        // ---- scale + causal mask (diagonal tile only) ----
        const bool diag = (j == qt);
#pragma unroll
        for (int mi = 0; mi < 2; ++mi)
#pragma unroll
            for (int ni = 0; ni < 8; ++ni)
#pragma unroll
                for (int r = 0; r < 4; ++r) {
                    float s = sa[mi][ni][r] * 0.125f;   // 1/sqrt(64)
                    if (diag) {
                        int row = w * 32 + mi * 16 + quad * 4 + r;
                        int col = ni * 16 + l15;
                        if (col > row) s = -1e30f;
                    }
                    sa[mi][ni][r] = s;
                }
        // ---- online softmax (rows: quad*4+r, reduce across 16 lanes of quad) ----
#pragma unroll
        for (int mi = 0; mi < 2; ++mi) {
#pragma unroll
            for (int r = 0; r < 4; ++r) {
                float mx = sa[mi][0][r];
#pragma unroll
                for (int ni = 1; ni < 8; ++ni) mx = fmaxf(mx, sa[mi][ni][r]);
#pragma unroll
                for (int d = 1; d < 16; d <<= 1) mx = fmaxf(mx, __shfl_xor(mx, d, 64));
                float mnew = fmaxf(mstate[mi][r], mx);
                float alpha = __expf(mstate[mi][r] - mnew);
                float rsum = 0.f;
#pragma unroll
                for (int ni = 0; ni < 8; ++ni) {
                    float e = __expf(sa[mi][ni][r] - mnew);
                    sa[mi][ni][r] = e;
                    rsum += e;
                }
#pragma unroll
                for (int d = 1; d < 16; d <<= 1) rsum += __shfl_xor(rsum, d, 64);
                lstate[mi][r] = lstate[mi][r] * alpha + rsum;
                mstate[mi][r] = mnew;
#pragma unroll
                for (int ni = 0; ni < 4; ++ni) of[mi][ni][r] *= alpha;
            }
        }
        // ---- P (C-layout) -> LDS bf16, wave-private, no barrier needed ----
#pragma unroll
        for (int mi = 0; mi < 2; ++mi)
#pragma unroll
            for (int ni = 0; ni < 8; ++ni)
#pragma unroll
                for (int r = 0; r < 4; ++r)
                    Pw[(mi * 16 + quad * 4 + r) * 136 + ni * 16 + l15] = (bf16)sa[mi][ni][r];
        // ---- O += P V  (P A-frags from LDS; V B-frags from transposed Vt) ----
#pragma unroll
        for (int kk = 0; kk < 4; ++kk) {
            bf16x8 pa[2];
#pragma unroll
            for (int mi = 0; mi < 2; ++mi)
                pa[mi] = *(const bf16x8*)&Pw[(mi * 16 + l15) * 136 + kk * 32 + quad * 8];
#pragma unroll
            for (int ni = 0; ni < 4; ++ni) {
                bf16x8 vf = *(const bf16x8*)(Vt + vt_base + (size_t)(ni * 16 + l15) * SEQ +
                                             j * 128 + kk * 32 + quad * 8);
#pragma unroll
                for (int mi = 0; mi < 2; ++mi)
                    of[mi][ni] = MFMA16(pa[mi], vf, of[mi][ni]);
            }
        }
    }
    // ---- normalize and store X[b][s][h*64+d] ----
#pragma unroll
    for (int mi = 0; mi < 2; ++mi)
#pragma unroll
        for (int ni = 0; ni < 4; ++ni)
#pragma unroll
            for (int r = 0; r < 4; ++r) {
                float o = of[mi][ni][r] / lstate[mi][r];
                X[qk_base + (size_t)(qt * 128 + w * 32 + mi * 16 + quad * 4 + r) * DM +
                  ni * 16 + l15] = (bf16)o;
            }
}

// ---------------- launcher ----------------
extern "C" void kernel_launch(void* const* d_in, const int* in_sizes, int n_in,
                              void* d_out, int out_size, void* d_ws, size_t ws_size,
                              hipStream_t stream) {
    const float* q  = (const float*)d_in[0];
    const float* k  = (const float*)d_in[1];
    const float* v  = (const float*)d_in[2];
    // d_in[3] = mask: always causal tril, handled analytically
    const float* wq = (const float*)d_in[4];
    const float* bq = (const float*)d_in[5];
    const float* wk = (const float*)d_in[6];
    const float* bk = (const float*)d_in[7];
    const float* wv = (const float*)d_in[8];
    const float* bv = (const float*)d_in[9];
    const float* wo = (const float*)d_in[10];
    const float* bo = (const float*)d_in[11];
    float* out = (float*)d_out;

    uint8_t* ws = (uint8_t*)d_ws;
    const size_t SZ_ACT = (size_t)MROWS * DM * sizeof(bf16);  // 8 MB
    const size_t SZ_W   = (size_t)DM * DM * sizeof(bf16);     // 2 MB
    bf16* qb  = (bf16*)(ws);
    bf16* kb  = (bf16*)(ws + SZ_ACT);
    bf16* vb  = (bf16*)(ws + 2 * SZ_ACT);
    bf16* wqb = (bf16*)(ws + 3 * SZ_ACT);
    bf16* wkb = (bf16*)(ws + 3 * SZ_ACT + SZ_W);
    bf16* wvb = (bf16*)(ws + 3 * SZ_ACT + 2 * SZ_W);
    bf16* wob = (bf16*)(ws + 3 * SZ_ACT + 3 * SZ_W);
    bf16* Qp  = (bf16*)(ws + 3 * SZ_ACT + 4 * SZ_W);
    bf16* Kp  = (bf16*)(ws + 4 * SZ_ACT + 4 * SZ_W);
    bf16* Vp  = (bf16*)(ws + 5 * SZ_ACT + 4 * SZ_W);
    bf16* Vt  = (bf16*)(ws + 6 * SZ_ACT + 4 * SZ_W);
    bf16* X   = (bf16*)(ws + 7 * SZ_ACT + 4 * SZ_W);
    // total: 8*SZ_ACT + 4*SZ_W = 72 MB

    // 1) convert everything to bf16
    {
        long total_vec4 = 3L * MROWS * DM / 4 + 4L * DM * DM / 4;  // 4,194,304
        k_convert<<<dim3((unsigned)(total_vec4 / 256)), 256, 0, stream>>>(
            q, k, v, wq, wk, wv, wo, qb, kb, vb, wqb, wkb, wvb, wob);
    }
    // 2) fused QKV projections (z selects q/k/v)
    k_gemm_qkv<<<dim3(DM / 128, MROWS / 128, 3), 256, 0, stream>>>(
        qb, kb, vb, wqb, wkb, wvb, bq, bk, bv, Qp, Kp, Vp);
    // 3) transpose V per head
    k_transpose_v<<<dim3(SEQ / 64, NH, BATCH), 256, 0, stream>>>(Vp, Vt);
    // 4) causal flash attention
    k_flash<<<dim3(SEQ / 128, BATCH * NH), 256, 0, stream>>>(Qp, Kp, Vt, X);
    // 5) output projection -> fp32 out
    k_gemm_out<<<dim3(DM / 128, MROWS / 128, 1), 256, 0, stream>>>(X, wob, bo, out);
}

// Round 2
// 341.571 us; speedup vs baseline: 1.0074x; 1.0074x over previous
//
#include <hip/hip_runtime.h>
#include <hip/hip_bf16.h>
#include <cstdint>
#include <cstddef>

// ---- problem constants ----
#define BATCH 2
#define SEQ   2048
#define DM    1024
#define NH    16
#define DK    64
#define MROWS (BATCH*SEQ)   // 4096

typedef __bf16 bf16;
typedef float  f32x4  __attribute__((ext_vector_type(4)));
typedef bf16   bf16x8 __attribute__((ext_vector_type(8)));
typedef bf16   bf16x4 __attribute__((ext_vector_type(4)));

#define MFMA16(a, b, c) __builtin_amdgcn_mfma_f32_16x16x32_bf16(a, b, c, 0, 0, 0)

// async global->LDS, 16B per lane; LDS dest is wave-uniform base + lane*16
__device__ __forceinline__ void llds16(const void* gc, void* l) {
    void* g = (void*)gc;  // drop const
    __builtin_amdgcn_global_load_lds(
        (__attribute__((address_space(1))) uint32_t*)g,
        (__attribute__((address_space(3))) uint32_t*)l,
        16, 0, 0);
}

// ---------------- fused fp32 -> bf16 convert (q,k,v + 4 weights) ----------------
__global__ __launch_bounds__(256) void k_convert(
    const float* __restrict__ q, const float* __restrict__ k, const float* __restrict__ v,
    const float* __restrict__ wq, const float* __restrict__ wk, const float* __restrict__ wv,
    const float* __restrict__ wo,
    bf16* __restrict__ qb, bf16* __restrict__ kb, bf16* __restrict__ vb,
    bf16* __restrict__ wqb, bf16* __restrict__ wkb, bf16* __restrict__ wvb,
    bf16* __restrict__ wob) {
    long t = (long)blockIdx.x * blockDim.x + threadIdx.x;   // one float4 per thread
    const long NQ = (long)MROWS * DM / 4;                   // 1,048,576 vec4 per activation
    const long NW = (long)DM * DM / 4;                      // 262,144 vec4 per weight
    const float* src; bf16* dst; long off;
    if (t < NQ)            { src = q;  dst = qb;  off = t; }
    else if (t < 2*NQ)     { src = k;  dst = kb;  off = t - NQ; }
    else if (t < 3*NQ)     { src = v;  dst = vb;  off = t - 2*NQ; }
    else {
        long u = t - 3*NQ;
        if (u < NW)        { src = wq; dst = wqb; off = u; }
        else if (u < 2*NW) { src = wk; dst = wkb; off = u - NW; }
        else if (u < 3*NW) { src = wv; dst = wvb; off = u - 2*NW; }
        else               { src = wo; dst = wob; off = u - 3*NW; }
    }
    f32x4 x = *(const f32x4*)(src + off * 4);
    bf16x4 y;
    y[0] = (bf16)x[0]; y[1] = (bf16)x[1]; y[2] = (bf16)x[2]; y[3] = (bf16)x[3];
    *(bf16x4*)(dst + off * 4) = y;
}

// ---------------- m97-style GEMM: C[M,N] = A[M,K] * W[N,K]^T + bias ----------------
// 128x128 tile, BK=32, 4 waves in 2x2, each wave 64x64 as 4x4 of 16x16x32 MFMA.
template <typename OutT>
__device__ __forceinline__ void gemm128(const bf16* __restrict__ A, const bf16* __restrict__ W,
                                        const float* __restrict__ bias, OutT* __restrict__ C,
                                        int m0, int n0) {
    constexpr int K = DM, N = DM, BK = 32;
    __shared__ bf16 sA[128 * BK];
    __shared__ bf16 sB[128 * BK];
    const int tid = threadIdx.x;
    const int l = tid & 63, w = tid >> 6;
    const int quad = l >> 4, l15 = l & 15;
    const int wm = w & 1, wn = w >> 1;

    f32x4 acc[4][4] = {};

    for (int k0 = 0; k0 < K; k0 += BK) {
        // stage A[128xBK], B[128xBK]; each wave: 2 issues of 16 rows per matrix
#pragma unroll
        for (int i = 0; i < 2; ++i) {
            int r16 = w * 32 + i * 16;
            const bf16* ga = A + (size_t)(m0 + r16 + (l >> 2)) * K + k0 + (l & 3) * 8;
            const bf16* gb = W + (size_t)(n0 + r16 + (l >> 2)) * K + k0 + (l & 3) * 8;
            llds16(ga, &sA[r16 * BK]);
            llds16(gb, &sB[r16 * BK]);
        }
        __syncthreads();

        bf16x8 af[4], bfr[4];
#pragma unroll
        for (int mi = 0; mi < 4; ++mi)
            af[mi] = *(const bf16x8*)&sA[(wm * 64 + mi * 16 + l15) * BK + quad * 8];
#pragma unroll
        for (int ni = 0; ni < 4; ++ni)
            bfr[ni] = *(const bf16x8*)&sB[(wn * 64 + ni * 16 + l15) * BK + quad * 8];
#pragma unroll
        for (int mi = 0; mi < 4; ++mi)
#pragma unroll
            for (int ni = 0; ni < 4; ++ni)
                acc[mi][ni] = MFMA16(af[mi], bfr[ni], acc[mi][ni]);
        __syncthreads();
    }

    // epilogue: C/D layout col=lane&15, row=quad*4+reg
#pragma unroll
    for (int mi = 0; mi < 4; ++mi) {
#pragma unroll
        for (int ni = 0; ni < 4; ++ni) {
            int col = n0 + wn * 64 + ni * 16 + l15;
            float bv = bias[col];
            int rbase = m0 + wm * 64 + mi * 16 + quad * 4;
#pragma unroll
            for (int r = 0; r < 4; ++r) {
                float val = acc[mi][ni][r] + bv;
                C[(size_t)(rbase + r) * N + col] = (OutT)val;
            }
        }
    }
}

__global__ __launch_bounds__(256) void k_gemm_qkv(
    const bf16* __restrict__ qb, const bf16* __restrict__ kb, const bf16* __restrict__ vb,
    const bf16* __restrict__ wqb, const bf16* __restrict__ wkb, const bf16* __restrict__ wvb,
    const float* __restrict__ bq, const float* __restrict__ bk, const float* __restrict__ bv,
    bf16* __restrict__ Qp, bf16* __restrict__ Kp, bf16* __restrict__ Vp) {
    int z = blockIdx.z;
    const bf16* A = (z == 0) ? qb : (z == 1) ? kb : vb;
    const bf16* W = (z == 0) ? wqb : (z == 1) ? wkb : wvb;
    const float* bi = (z == 0) ? bq : (z == 1) ? bk : bv;
    bf16* C = (z == 0) ? Qp : (z == 1) ? Kp : Vp;
    gemm128<bf16>(A, W, bi, C, blockIdx.y * 128, blockIdx.x * 128);
}

__global__ __launch_bounds__(256) void k_gemm_out(
    const bf16* __restrict__ X, const bf16* __restrict__ wob,
    const float* __restrict__ bo, float* __restrict__ out) {
    gemm128<float>(X, wob, bo, out, blockIdx.y * 128, blockIdx.x * 128);
}

// ---------------- V transpose per head: Vt[b][h][d][s] = Vp[b][s][h*64+d] ----------------
__global__ __launch_bounds__(256) void k_transpose_v(const bf16* __restrict__ Vp,
                                                     bf16* __restrict__ Vt) {
    const int b = blockIdx.z, h = blockIdx.y, s0 = blockIdx.x * 64;
    __shared__ bf16 t[64 * 65];
    const int tid = threadIdx.x;
    const int r8 = tid >> 3, c8 = (tid & 7) * 8;
#pragma unroll
    for (int i = 0; i < 2; ++i) {
        int s = i * 32 + r8;
        bf16x8 v = *(const bf16x8*)(Vp + (size_t)(b * SEQ + s0 + s) * DM + h * DK + c8);
#pragma unroll
        for (int j = 0; j < 8; ++j) t[s * 65 + c8 + j] = v[j];
    }
    __syncthreads();
#pragma unroll
    for (int i = 0; i < 2; ++i) {
        int d = i * 32 + r8;
        bf16x8 v;
#pragma unroll
        for (int j = 0; j < 8; ++j) v[j] = t[(c8 + j) * 65 + d];
        *(bf16x8*)(Vt + ((size_t)(b * NH + h) * DK + d) * SEQ + s0 + c8) = v;
    }
}

// ---------------- causal flash attention ----------------
// 128 threads = 2 waves; each wave owns 16 Q rows; block = 32 Q rows.
// grid (64, 32): x -> swizzled 32-row Q tile, y -> (b,h).
// qt = (x + 2y) & 63 spreads the causal work (1..16 KV tiles) across CUs.
// Q/K frags direct global->reg; V frags from transposed Vt; P via wave-private LDS.
__global__ __launch_bounds__(128, 4) void k_flash(const bf16* __restrict__ Qp,
                                                  const bf16* __restrict__ Kp,
                                                  const bf16* __restrict__ Vt,
                                                  bf16* __restrict__ X) {
    const int bh = blockIdx.y;
    const int qt = (blockIdx.x + 2 * blockIdx.y) & 63;   // swizzled 32-row tile idx
    const int b = bh >> 4, h = bh & 15;
    __shared__ bf16 P[32 * 136];     // stride 136: 16B-aligned rows, 2-way-free banks
    const int tid = threadIdx.x, l = tid & 63, w = tid >> 6;   // w in {0,1}
    const int quad = l >> 4, l15 = l & 15;
    const int row0 = qt * 32 + w * 16;                   // wave's global Q row base

    const size_t qk_base = (size_t)b * SEQ * DM + h * DK;
    const size_t vt_base = (size_t)(b * NH + h) * DK * SEQ;
    bf16* Pw = &P[(w * 16) * 136];   // wave-private region

    // persistent Q fragments: rows row0 + l15, k = kk*32 + quad*8
    bf16x8 qf[2];
#pragma unroll
    for (int kk = 0; kk < 2; ++kk)
        qf[kk] = *(const bf16x8*)(Qp + qk_base + (size_t)(row0 + l15) * DM + kk * 32 + quad * 8);

    float mstate[4], lstate[4];
#pragma unroll
    for (int r = 0; r < 4; ++r) { mstate[r] = -1e30f; lstate[r] = 0.f; }
    f32x4 of[4] = {};

    const int jmax = (qt >> 2) + 1;          // # of 128-wide KV tiles (causal)
    const float SC = 0.18033688f;            // 0.125 * log2(e): softmax in exp2 domain

    for (int j = 0; j < jmax; ++j) {
        // ---- S = Q K^T (per wave: 16 x 128) ----
        f32x4 sa[8] = {};
#pragma unroll
        for (int ni = 0; ni < 8; ++ni) {
            const bf16* kr = Kp + qk_base + (size_t)(j * 128 + ni * 16 + l15) * DM + quad * 8;
            bf16x8 kf0 = *(const bf16x8*)(kr);
            bf16x8 kf1 = *(const bf16x8*)(kr + 32);
            sa[ni] = MFMA16(qf[0], kf0, sa[ni]);
            sa[ni] = MFMA16(qf[1], kf1, sa[ni]);
        }
        // ---- scale into log2 domain + causal mask (last tile only) ----
        const bool diag = (j == jmax - 1);
#pragma unroll
        for (int ni = 0; ni < 8; ++ni)
#pragma unroll
            for (int r = 0; r < 4; ++r) {
                float s = sa[ni][r] * SC;
                if (diag) {
                    int row = row0 + quad * 4 + r;
                    int col = j * 128 + ni * 16 + l15;
                    if (col > row) s = -1e30f;
                }
                sa[ni][r] = s;
            }
        // ---- online softmax (rows quad*4+r, reduce across the 16 lanes of quad) ----
#pragma unroll
        for (int r = 0; r < 4; ++r) {
            float mx = sa[0][r];
#pragma unroll
            for (int ni = 1; ni < 8; ++ni) mx = fmaxf(mx, sa[ni][r]);
#pragma unroll
            for (int d = 1; d < 16; d <<= 1) mx = fmaxf(mx, __shfl_xor(mx, d, 64));
            float mnew = fmaxf(mstate[r], mx);
            float alpha = __builtin_amdgcn_exp2f(mstate[r] - mnew);
            float rsum = 0.f;
#pragma unroll
            for (int ni = 0; ni < 8; ++ni) {
                float e = __builtin_amdgcn_exp2f(sa[ni][r] - mnew);
                sa[ni][r] = e;
                rsum += e;
            }
#pragma unroll
            for (int d = 1; d < 16; d <<= 1) rsum += __shfl_xor(rsum, d, 64);
            lstate[r] = lstate[r] * alpha + rsum;
            mstate[r] = mnew;
#pragma unroll
            for (int ni = 0; ni < 4; ++ni) of[ni][r] *= alpha;
        }
        // ---- P (C-layout) -> LDS bf16, wave-private, no barrier needed ----
#pragma unroll
        for (int ni = 0; ni < 8; ++ni)
#pragma unroll
            for (int r = 0; r < 4; ++r)
                Pw[(quad * 4 + r) * 136 + ni * 16 + l15] = (bf16)sa[ni][r];
        // ---- O += P V  (P A-frags from LDS; V B-frags from transposed Vt) ----
#pragma unroll
        for (int kk = 0; kk < 4; ++kk) {
            bf16x8 pa = *(const bf16x8*)&Pw[l15 * 136 + kk * 32 + quad * 8];
#pragma unroll
            for (int ni = 0; ni < 4; ++ni) {
                bf16x8 vf = *(const bf16x8*)(Vt + vt_base + (size_t)(ni * 16 + l15) * SEQ +
                                             j * 128 + kk * 32 + quad * 8);
                of[ni] = MFMA16(pa, vf, of[ni]);
            }
        }
    }
    // ---- normalize and store X[b][s][h*64+d] ----
#pragma unroll
    for (int ni = 0; ni < 4; ++ni)
#pragma unroll
        for (int r = 0; r < 4; ++r) {
            float o = of[ni][r] / lstate[r];
            X[qk_base + (size_t)(row0 + quad * 4 + r) * DM + ni * 16 + l15] = (bf16)o;
        }
}

// ---------------- launcher ----------------
extern "C" void kernel_launch(void* const* d_in, const int* in_sizes, int n_in,
                              void* d_out, int out_size, void* d_ws, size_t ws_size,
                              hipStream_t stream) {
    const float* q  = (const float*)d_in[0];
    const float* k  = (const float*)d_in[1];
    const float* v  = (const float*)d_in[2];
    // d_in[3] = mask: always causal tril, handled analytically
    const float* wq = (const float*)d_in[4];
    const float* bq = (const float*)d_in[5];
    const float* wk = (const float*)d_in[6];
    const float* bk = (const float*)d_in[7];
    const float* wv = (const float*)d_in[8];
    const float* bv = (const float*)d_in[9];
    const float* wo = (const float*)d_in[10];
    const float* bo = (const float*)d_in[11];
    float* out = (float*)d_out;

    uint8_t* ws = (uint8_t*)d_ws;
    const size_t SZ_ACT = (size_t)MROWS * DM * sizeof(bf16);  // 8 MB
    const size_t SZ_W   = (size_t)DM * DM * sizeof(bf16);     // 2 MB
    bf16* qb  = (bf16*)(ws);
    bf16* kb  = (bf16*)(ws + SZ_ACT);
    bf16* vb  = (bf16*)(ws + 2 * SZ_ACT);
    bf16* wqb = (bf16*)(ws + 3 * SZ_ACT);
    bf16* wkb = (bf16*)(ws + 3 * SZ_ACT + SZ_W);
    bf16* wvb = (bf16*)(ws + 3 * SZ_ACT + 2 * SZ_W);
    bf16* wob = (bf16*)(ws + 3 * SZ_ACT + 3 * SZ_W);
    bf16* Qp  = (bf16*)(ws + 3 * SZ_ACT + 4 * SZ_W);
    bf16* Kp  = (bf16*)(ws + 4 * SZ_ACT + 4 * SZ_W);
    bf16* Vp  = (bf16*)(ws + 5 * SZ_ACT + 4 * SZ_W);
    bf16* Vt  = (bf16*)(ws + 6 * SZ_ACT + 4 * SZ_W);
    bf16* X   = (bf16*)(ws + 7 * SZ_ACT + 4 * SZ_W);
    // total: 8*SZ_ACT + 4*SZ_W = 72 MB

    // 1) convert everything to bf16
    {
        long total_vec4 = 3L * MROWS * DM / 4 + 4L * DM * DM / 4;  // 4,194,304
        k_convert<<<dim3((unsigned)(total_vec4 / 256)), 256, 0, stream>>>(
            q, k, v, wq, wk, wv, wo, qb, kb, vb, wqb, wkb, wvb, wob);
    }
    // 2) fused QKV projections (z selects q/k/v)
    k_gemm_qkv<<<dim3(DM / 128, MROWS / 128, 3), 256, 0, stream>>>(
        qb, kb, vb, wqb, wkb, wvb, bq, bk, bv, Qp, Kp, Vp);
    // 3) transpose V per head
    k_transpose_v<<<dim3(SEQ / 64, NH, BATCH), 256, 0, stream>>>(Vp, Vt);
    // 4) causal flash attention (32-row Q tiles, swizzled)
    k_flash<<<dim3(SEQ / 32, BATCH * NH), 128, 0, stream>>>(Qp, Kp, Vt, X);
    // 5) output projection -> fp32 out
    k_gemm_out<<<dim3(DM / 128, MROWS / 128, 1), 256, 0, stream>>>(X, wob, bo, out);
}

// Round 3
// 254.524 us; speedup vs baseline: 1.3520x; 1.3420x over previous
//
#include <hip/hip_runtime.h>
#include <hip/hip_bf16.h>
#include <cstdint>
#include <cstddef>

// ---- problem constants ----
#define BATCH 2
#define SEQ   2048
#define DM    1024
#define NH    16
#define DK    64
#define MROWS (BATCH*SEQ)   // 4096

typedef __bf16 bf16;
typedef float  f32x4  __attribute__((ext_vector_type(4)));
typedef bf16   bf16x8 __attribute__((ext_vector_type(8)));
typedef bf16   bf16x4 __attribute__((ext_vector_type(4)));
typedef short  s16x4  __attribute__((ext_vector_type(4)));

#define MFMA32(a, b, c) __builtin_amdgcn_mfma_f32_16x16x32_bf16(a, b, c, 0, 0, 0)
// 16x16x16 bf16 (K=16): A/B frag = 4 bf16 (lane: i=l&15, k=quad*4+e); C/D as usual
#define MFMA1K(a, b, c) __builtin_amdgcn_mfma_f32_16x16x16bf16_1k(a, b, c, 0, 0, 0)

union HU { bf16x8 v; s16x4 h[2]; };   // split 16B frag into two K=16 halves
union PU { bf16x4 b; s16x4 s; };      // pack 4 bf16 -> s16x4

// async global->LDS, 16B per lane; LDS dest is wave-uniform base + lane*16
__device__ __forceinline__ void llds16(const void* gc, void* l) {
    void* g = (void*)gc;
    __builtin_amdgcn_global_load_lds(
        (__attribute__((address_space(1))) uint32_t*)g,
        (__attribute__((address_space(3))) uint32_t*)l,
        16, 0, 0);
}

// ---------------- fused fp32 -> bf16 convert (q,k,v + 4 weights) ----------------
__global__ __launch_bounds__(256) void k_convert(
    const float* __restrict__ q, const float* __restrict__ k, const float* __restrict__ v,
    const float* __restrict__ wq, const float* __restrict__ wk, const float* __restrict__ wv,
    const float* __restrict__ wo,
    bf16* __restrict__ qb, bf16* __restrict__ kb, bf16* __restrict__ vb,
    bf16* __restrict__ wqb, bf16* __restrict__ wkb, bf16* __restrict__ wvb,
    bf16* __restrict__ wob) {
    long t = (long)blockIdx.x * blockDim.x + threadIdx.x;   // one float4 per thread
    const long NQ = (long)MROWS * DM / 4;
    const long NW = (long)DM * DM / 4;
    const float* src; bf16* dst; long off;
    if (t < NQ)            { src = q;  dst = qb;  off = t; }
    else if (t < 2*NQ)     { src = k;  dst = kb;  off = t - NQ; }
    else if (t < 3*NQ)     { src = v;  dst = vb;  off = t - 2*NQ; }
    else {
        long u = t - 3*NQ;
        if (u < NW)        { src = wq; dst = wqb; off = u; }
        else if (u < 2*NW) { src = wk; dst = wkb; off = u - NW; }
        else if (u < 3*NW) { src = wv; dst = wvb; off = u - 2*NW; }
        else               { src = wo; dst = wob; off = u - 3*NW; }
    }
    f32x4 x = *(const f32x4*)(src + off * 4);
    bf16x4 y;
    y[0] = (bf16)x[0]; y[1] = (bf16)x[1]; y[2] = (bf16)x[2]; y[3] = (bf16)x[3];
    *(bf16x4*)(dst + off * 4) = y;
}

// ---------------- m97-style GEMM mainloop: acc = A[M,K] * B[N,K]^T ----------------
// 128x128 tile, BK=32, 4 waves in 2x2, each wave 64x64 as 4x4 of 16x16x32 MFMA.
// Produces acc only; epilogue is kernel-specific.
__device__ __forceinline__ void gemm_main(const bf16* __restrict__ A, const bf16* __restrict__ B,
                                          int m0, int n0, f32x4 acc[4][4]) {
    constexpr int K = DM, BK = 32;
    __shared__ bf16 sA[128 * BK];
    __shared__ bf16 sB[128 * BK];
    const int tid = threadIdx.x;
    const int l = tid & 63, w = tid >> 6;
    const int quad = l >> 4, l15 = l & 15;
    const int wm = w & 1, wn = w >> 1;

    for (int k0 = 0; k0 < K; k0 += BK) {
#pragma unroll
        for (int i = 0; i < 2; ++i) {
            int r16 = w * 32 + i * 16;
            const bf16* ga = A + (size_t)(m0 + r16 + (l >> 2)) * K + k0 + (l & 3) * 8;
            const bf16* gb = B + (size_t)(n0 + r16 + (l >> 2)) * K + k0 + (l & 3) * 8;
            llds16(ga, &sA[r16 * BK]);
            llds16(gb, &sB[r16 * BK]);
        }
        __syncthreads();

        bf16x8 af[4], bfr[4];
#pragma unroll
        for (int mi = 0; mi < 4; ++mi)
            af[mi] = *(const bf16x8*)&sA[(wm * 64 + mi * 16 + l15) * BK + quad * 8];
#pragma unroll
        for (int ni = 0; ni < 4; ++ni)
            bfr[ni] = *(const bf16x8*)&sB[(wn * 64 + ni * 16 + l15) * BK + quad * 8];
#pragma unroll
        for (int mi = 0; mi < 4; ++mi)
#pragma unroll
            for (int ni = 0; ni < 4; ++ni)
                acc[mi][ni] = MFMA32(af[mi], bfr[ni], acc[mi][ni]);
        __syncthreads();
    }
}

// ---- Q/K projection, transposed (D[feature][s] = W·actT), epilogue -> fragment-major ----
// Frag entry (bh, kb16 = s/16, p = d-pair): 1KB; lane l holds s=base+l&15,
// d = 32p + (l>>4)*4 + e (e<4) and +16 (e>=4)  == 16x16x16 A/B frag packing.
__global__ __launch_bounds__(256) void k_gemm_qk(
    const bf16* __restrict__ qb, const bf16* __restrict__ kb,
    const bf16* __restrict__ wqb, const bf16* __restrict__ wkb,
    const float* __restrict__ bq, const float* __restrict__ bk,
    bf16* __restrict__ Qf, bf16* __restrict__ Kf) {
    const int z = blockIdx.z;
    const bf16* A = z ? wkb : wqb;          // weights: rows = out features
    const bf16* B = z ? kb : qb;            // activations: rows = s
    const float* bias = z ? bk : bq;
    bf16* out = z ? Kf : Qf;
    const float scale = z ? 1.0f : 0.18033688f;   // Q carries 0.125*log2(e)

    const int m0 = blockIdx.y * 128;        // feature block
    const int n0 = blockIdx.x * 128;        // s block
    f32x4 acc[4][4] = {};
    gemm_main(A, B, m0, n0, acc);

    const int tid = threadIdx.x, l = tid & 63, w = tid >> 6;
    const int quad = l >> 4, l15 = l & 15;
    const int wm = w & 1, wn = w >> 1;

    float bias_rv[4][4];
#pragma unroll
    for (int mi = 0; mi < 4; ++mi)
#pragma unroll
        for (int r = 0; r < 4; ++r)
            bias_rv[mi][r] = bias[m0 + wm * 64 + mi * 16 + quad * 4 + r];

#pragma unroll
    for (int ni = 0; ni < 4; ++ni) {
        int col = n0 + wn * 64 + ni * 16 + l15;     // global s
        int b = col >> 11, s = col & 2047;
        int kb16 = s >> 4;
#pragma unroll
        for (int mi2 = 0; mi2 < 4; mi2 += 2) {
            bf16x8 pack;
#pragma unroll
            for (int half = 0; half < 2; ++half)
#pragma unroll
                for (int r = 0; r < 4; ++r) {
                    float x = (acc[mi2 + half][ni][r] + bias_rv[mi2 + half][r]) * scale;
                    pack[half * 4 + r] = (bf16)x;
                }
            int drow = m0 + wm * 64 + mi2 * 16;
            int h = (drow >> 6) & 15, p = (drow >> 5) & 1;
            size_t entry = ((size_t)((b * NH + h) * 128 + kb16)) * 2 + p;
            *(bf16x8*)(out + entry * 512 + (size_t)(quad * 16 + l15) * 8) = pack;
        }
    }
}

// ---- V projection, normal (D[s][feature]), epilogue -> fragment-major Vf ----
// Frag entry (bh, scp = s/32, nid = d/16): lane l holds d = nid*16 + (l&15),
// n(local s) = {half0: (l>>4)*4+e, half1: 16+(l>>4)*4+e}
__global__ __launch_bounds__(256) void k_gemm_v(
    const bf16* __restrict__ vb, const bf16* __restrict__ wvb,
    const float* __restrict__ bv, bf16* __restrict__ Vf) {
    const int m0 = blockIdx.y * 128;        // s block
    const int n0 = blockIdx.x * 128;        // feature block
    f32x4 acc[4][4] = {};
    gemm_main(vb, wvb, m0, n0, acc);

    const int tid = threadIdx.x, l = tid & 63, w = tid >> 6;
    const int quad = l >> 4, l15 = l & 15;
    const int wm = w & 1, wn = w >> 1;

#pragma unroll
    for (int ni = 0; ni < 4; ++ni) {
        int col = n0 + wn * 64 + ni * 16 + l15;     // global feature
        int h = col >> 6, nid = (col >> 4) & 3;
        float bias_v = bv[col];
#pragma unroll
        for (int mi2 = 0; mi2 < 4; mi2 += 2) {
            bf16x8 pack;
#pragma unroll
            for (int half = 0; half < 2; ++half)
#pragma unroll
                for (int r = 0; r < 4; ++r)
                    pack[half * 4 + r] = (bf16)(acc[mi2 + half][ni][r] + bias_v);
            int row = m0 + wm * 64 + mi2 * 16;
            int b = row >> 11, sl = row & 2047;
            size_t entry = ((size_t)(b * NH + h) * 64 + (sl >> 5)) * 4 + nid;
            *(bf16x8*)(Vf + entry * 512 + (size_t)(quad * 16 + l15) * 8) = pack;
        }
    }
}

// ---- output projection: row-major fp32 + bias ----
__global__ __launch_bounds__(256) void k_gemm_out(
    const bf16* __restrict__ X, const bf16* __restrict__ wob,
    const float* __restrict__ bo, float* __restrict__ out) {
    const int m0 = blockIdx.y * 128, n0 = blockIdx.x * 128;
    f32x4 acc[4][4] = {};
    gemm_main(X, wob, m0, n0, acc);

    const int tid = threadIdx.x, l = tid & 63, w = tid >> 6;
    const int quad = l >> 4, l15 = l & 15;
    const int wm = w & 1, wn = w >> 1;
#pragma unroll
    for (int mi = 0; mi < 4; ++mi)
#pragma unroll
        for (int ni = 0; ni < 4; ++ni) {
            int col = n0 + wn * 64 + ni * 16 + l15;
            float bias_v = bo[col];
            int rbase = m0 + wm * 64 + mi * 16 + quad * 4;
#pragma unroll
            for (int r = 0; r < 4; ++r)
                out[(size_t)(rbase + r) * DM + col] = acc[mi][ni][r] + bias_v;
        }
}

// ---------------- causal flash attention, all-coalesced fragment loads ----------------
// grid (bh=32, qt=32): XCD = blockId%8 -> bh%8 pins each bh's K/V (512KB) to one XCD L2.
// 128 thr = 2 waves; wave owns 32 Q rows (2 m-tiles); KV j-tile = 64 keys.
// S^T = K·Q^T via 16x16x16 MFMA -> P stays in registers as A-frags for P·V.
__global__ __launch_bounds__(128, 3) void k_flash(const bf16* __restrict__ Qf,
                                                  const bf16* __restrict__ Kf,
                                                  const bf16* __restrict__ Vf,
                                                  bf16* __restrict__ X) {
    const int bh = blockIdx.x, qt = blockIdx.y;
    const int b = bh >> 4, h = bh & 15;
    const int tid = threadIdx.x, w = tid >> 6, l = tid & 63;
    const int quad = l >> 4, l15 = l & 15;
    __shared__ bf16 xs[2][32 * 72];         // per-wave X repack (72: pad vs bank conflicts)

    const bf16* kf = Kf + (size_t)bh * 128 * 1024;   // 128 kb * 2 p * 512 elems
    const bf16* vf = Vf + (size_t)bh * 64 * 4 * 512; // 64 scp * 4 nid * 512
    const bf16* qfp = Qf + (size_t)bh * 128 * 1024;
    const int row0 = qt * 64 + w * 32;

    // persistent Q frags (coalesced): [mt][p], each 16B = two K=16 halves
    HU q16[2][2];
#pragma unroll
    for (int mt = 0; mt < 2; ++mt)
#pragma unroll
        for (int p = 0; p < 2; ++p)
            q16[mt][p].v = *(const bf16x8*)(qfp + ((size_t)((row0 >> 4) + mt) * 2 + p) * 512 + (size_t)l * 8);

    float ms[2] = {-1e30f, -1e30f}, ls[2] = {0.f, 0.f};
    f32x4 of[2][4] = {};

    for (int j = 0; j <= qt; ++j) {
        // ---- K frags (8 coalesced 16B loads) ----
        HU kl[4][2];
#pragma unroll
        for (int ni = 0; ni < 4; ++ni)
#pragma unroll
            for (int p = 0; p < 2; ++p)
                kl[ni][p].v = *(const bf16x8*)(kf + ((size_t)(j * 4 + ni) * 2 + p) * 512 + (size_t)l * 8);

        // ---- S^T = K·Q^T : sa[mt][ni], lane: m = l15, n = ni*16 + quad*4 + r ----
        f32x4 sa[2][4] = {};
#pragma unroll
        for (int kc = 0; kc < 4; ++kc)
#pragma unroll
            for (int ni = 0; ni < 4; ++ni)
#pragma unroll
                for (int mt = 0; mt < 2; ++mt)
                    sa[mt][ni] = MFMA1K(kl[ni][kc >> 1].h[kc & 1], q16[mt][kc >> 1].h[kc & 1],
                                        sa[mt][ni]);

        // ---- causal mask (diag tile only); scores already in log2 domain ----
        if (j == qt) {
#pragma unroll
            for (int mt = 0; mt < 2; ++mt)
#pragma unroll
                for (int ni = 0; ni < 4; ++ni)
#pragma unroll
                    for (int r = 0; r < 4; ++r) {
                        int n = j * 64 + ni * 16 + quad * 4 + r;
                        int m = row0 + mt * 16 + l15;
                        if (n > m) sa[mt][ni][r] = -1e30f;
                    }
        }

        // ---- online softmax (mostly in-lane; 2 shuffles per reduce) ----
        s16x4 pf[2][4];
#pragma unroll
        for (int mt = 0; mt < 2; ++mt) {
            float mx = sa[mt][0][0];
#pragma unroll
            for (int ni = 0; ni < 4; ++ni)
#pragma unroll
                for (int r = 0; r < 4; ++r) mx = fmaxf(mx, sa[mt][ni][r]);
            mx = fmaxf(mx, __shfl_xor(mx, 16, 64));
            mx = fmaxf(mx, __shfl_xor(mx, 32, 64));
            float mnew = fmaxf(ms[mt], mx);
            float al = __builtin_amdgcn_exp2f(ms[mt] - mnew);
            ms[mt] = mnew;
            float sum = 0.f;
#pragma unroll
            for (int ni = 0; ni < 4; ++ni) {
                PU pu;
#pragma unroll
                for (int r = 0; r < 4; ++r) {
                    float e = __builtin_amdgcn_exp2f(sa[mt][ni][r] - mnew);
                    sum += e;
                    pu.b[r] = (bf16)e;
                }
                pf[mt][ni] = pu.s;
            }
            sum += __shfl_xor(sum, 16, 64);
            sum += __shfl_xor(sum, 32, 64);
            ls[mt] = ls[mt] * al + sum;
            // broadcast alpha from m=l15 layout to O rows (m = quad*4+r)
            float ar[4];
#pragma unroll
            for (int r = 0; r < 4; ++r) ar[r] = __shfl(al, quad * 4 + r, 16);
#pragma unroll
            for (int nid = 0; nid < 4; ++nid)
#pragma unroll
                for (int r = 0; r < 4; ++r) of[mt][nid][r] *= ar[r];
        }

        // ---- O += P·V (V frags coalesced; P from regs) ----
#pragma unroll
        for (int sp = 0; sp < 2; ++sp)
#pragma unroll
            for (int nid = 0; nid < 4; ++nid) {
                HU vl;
                vl.v = *(const bf16x8*)(vf + ((size_t)((j * 2 + sp) * 4 + nid)) * 512 + (size_t)l * 8);
#pragma unroll
                for (int mt = 0; mt < 2; ++mt) {
                    of[mt][nid] = MFMA1K(pf[mt][sp * 2 + 0], vl.h[0], of[mt][nid]);
                    of[mt][nid] = MFMA1K(pf[mt][sp * 2 + 1], vl.h[1], of[mt][nid]);
                }
            }
    }

    // ---- normalize, repack via LDS, coalesced store ----
#pragma unroll
    for (int mt = 0; mt < 2; ++mt) {
        float rv = 1.f / ls[mt];
        float rr[4];
#pragma unroll
        for (int r = 0; r < 4; ++r) rr[r] = __shfl(rv, quad * 4 + r, 16);
#pragma unroll
        for (int nid = 0; nid < 4; ++nid)
#pragma unroll
            for (int r = 0; r < 4; ++r)
                xs[w][(mt * 16 + quad * 4 + r) * 72 + nid * 16 + l15] =
                    (bf16)(of[mt][nid][r] * rr[r]);
    }
    // wave-private LDS; compiler inserts lgkmcnt waits
#pragma unroll
    for (int i = 0; i < 4; ++i) {
        int rowl = i * 8 + (l >> 3);
        bf16x8 vv = *(const bf16x8*)&xs[w][rowl * 72 + (l & 7) * 8];
        *(bf16x8*)(X + (size_t)(b * SEQ + row0 + rowl) * DM + h * 64 + (l & 7) * 8) = vv;
    }
}

// ---------------- launcher ----------------
extern "C" void kernel_launch(void* const* d_in, const int* in_sizes, int n_in,
                              void* d_out, int out_size, void* d_ws, size_t ws_size,
                              hipStream_t stream) {
    const float* q  = (const float*)d_in[0];
    const float* k  = (const float*)d_in[1];
    const float* v  = (const float*)d_in[2];
    // d_in[3] = mask: causal tril, handled analytically
    const float* wq = (const float*)d_in[4];
    const float* bq = (const float*)d_in[5];
    const float* wk = (const float*)d_in[6];
    const float* bk = (const float*)d_in[7];
    const float* wv = (const float*)d_in[8];
    const float* bv = (const float*)d_in[9];
    const float* wo = (const float*)d_in[10];
    const float* bo = (const float*)d_in[11];
    float* out = (float*)d_out;

    uint8_t* ws = (uint8_t*)d_ws;
    const size_t SZ_ACT = (size_t)MROWS * DM * sizeof(bf16);  // 8 MB
    const size_t SZ_W   = (size_t)DM * DM * sizeof(bf16);     // 2 MB
    bf16* qb  = (bf16*)(ws);
    bf16* kb  = (bf16*)(ws + SZ_ACT);
    bf16* vb  = (bf16*)(ws + 2 * SZ_ACT);
    bf16* wqb = (bf16*)(ws + 3 * SZ_ACT);
    bf16* wkb = (bf16*)(ws + 3 * SZ_ACT + SZ_W);
    bf16* wvb = (bf16*)(ws + 3 * SZ_ACT + 2 * SZ_W);
    bf16* wob = (bf16*)(ws + 3 * SZ_ACT + 3 * SZ_W);
    bf16* Qf  = (bf16*)(ws + 3 * SZ_ACT + 4 * SZ_W);
    bf16* Kf  = (bf16*)(ws + 4 * SZ_ACT + 4 * SZ_W);
    bf16* Vf  = (bf16*)(ws + 5 * SZ_ACT + 4 * SZ_W);
    bf16* X   = (bf16*)(ws + 6 * SZ_ACT + 4 * SZ_W);
    // total: 7*SZ_ACT + 4*SZ_W = 64 MB

    // 1) convert to bf16
    {
        long total_vec4 = 3L * MROWS * DM / 4 + 4L * DM * DM / 4;
        k_convert<<<dim3((unsigned)(total_vec4 / 256)), 256, 0, stream>>>(
            q, k, v, wq, wk, wv, wo, qb, kb, vb, wqb, wkb, wvb, wob);
    }
    // 2) Q,K projections (transposed, fragment-major out; Q carries softmax scale)
    k_gemm_qk<<<dim3(MROWS / 128, DM / 128, 2), 256, 0, stream>>>(
        qb, kb, wqb, wkb, bq, bk, Qf, Kf);
    // 3) V projection (fragment-major out)
    k_gemm_v<<<dim3(DM / 128, MROWS / 128), 256, 0, stream>>>(vb, wvb, bv, Vf);
    // 4) causal flash attention
    k_flash<<<dim3(BATCH * NH, SEQ / 64), 128, 0, stream>>>(Qf, Kf, Vf, X);
    // 5) output projection -> fp32
    k_gemm_out<<<dim3(DM / 128, MROWS / 128), 256, 0, stream>>>(X, wob, bo, out);
}

// Round 4
// 241.059 us; speedup vs baseline: 1.4275x; 1.0559x over previous
//
#include <hip/hip_runtime.h>
#include <hip/hip_bf16.h>
#include <cstdint>
#include <cstddef>

// ---- problem constants ----
#define BATCH 2
#define SEQ   2048
#define DM    1024
#define NH    16
#define DK    64
#define MROWS (BATCH*SEQ)   // 4096

typedef __bf16 bf16;
typedef float  f32x4  __attribute__((ext_vector_type(4)));
typedef bf16   bf16x8 __attribute__((ext_vector_type(8)));
typedef bf16   bf16x4 __attribute__((ext_vector_type(4)));
typedef short  s16x4  __attribute__((ext_vector_type(4)));

#define MFMA32(a, b, c) __builtin_amdgcn_mfma_f32_16x16x32_bf16(a, b, c, 0, 0, 0)
// 16x16x16 bf16 (K=16): A/B frag = 4 bf16 (lane: i=l&15, k=quad*4+e); C/D as usual
#define MFMA1K(a, b, c) __builtin_amdgcn_mfma_f32_16x16x16bf16_1k(a, b, c, 0, 0, 0)

union HU { bf16x8 v; s16x4 h[2]; };   // split 16B frag into two K=16 halves
union PU { bf16x4 b; s16x4 s; };      // pack 4 bf16 -> s16x4

// async global->LDS, 16B per lane; LDS dest is wave-uniform base + lane*16
__device__ __forceinline__ void llds16(const void* gc, void* l) {
    void* g = (void*)gc;
    __builtin_amdgcn_global_load_lds(
        (__attribute__((address_space(1))) uint32_t*)g,
        (__attribute__((address_space(3))) uint32_t*)l,
        16, 0, 0);
}

// ---------------- fused fp32 -> bf16 convert (q,k,v + 4 weights) ----------------
__global__ __launch_bounds__(256) void k_convert(
    const float* __restrict__ q, const float* __restrict__ k, const float* __restrict__ v,
    const float* __restrict__ wq, const float* __restrict__ wk, const float* __restrict__ wv,
    const float* __restrict__ wo,
    bf16* __restrict__ qb, bf16* __restrict__ kb, bf16* __restrict__ vb,
    bf16* __restrict__ wqb, bf16* __restrict__ wkb, bf16* __restrict__ wvb,
    bf16* __restrict__ wob) {
    long t = (long)blockIdx.x * blockDim.x + threadIdx.x;   // one float4 per thread
    const long NQ = (long)MROWS * DM / 4;
    const long NW = (long)DM * DM / 4;
    const float* src; bf16* dst; long off;
    if (t < NQ)            { src = q;  dst = qb;  off = t; }
    else if (t < 2*NQ)     { src = k;  dst = kb;  off = t - NQ; }
    else if (t < 3*NQ)     { src = v;  dst = vb;  off = t - 2*NQ; }
    else {
        long u = t - 3*NQ;
        if (u < NW)        { src = wq; dst = wqb; off = u; }
        else if (u < 2*NW) { src = wk; dst = wkb; off = u - NW; }
        else if (u < 3*NW) { src = wv; dst = wvb; off = u - 2*NW; }
        else               { src = wo; dst = wob; off = u - 3*NW; }
    }
    f32x4 x = *(const f32x4*)(src + off * 4);
    bf16x4 y;
    y[0] = (bf16)x[0]; y[1] = (bf16)x[1]; y[2] = (bf16)x[2]; y[3] = (bf16)x[3];
    *(bf16x4*)(dst + off * 4) = y;
}

// ---------------- m97-style GEMM mainloop: acc = A[M,K] * B[N,K]^T ----------------
// 128x128 tile, BK=32, 4 waves in 2x2, each wave 64x64 as 4x4 of 16x16x32 MFMA.
__device__ __forceinline__ void gemm_main(const bf16* __restrict__ A, const bf16* __restrict__ B,
                                          int m0, int n0, f32x4 acc[4][4]) {
    constexpr int K = DM, BK = 32;
    __shared__ bf16 sA[128 * BK];
    __shared__ bf16 sB[128 * BK];
    const int tid = threadIdx.x;
    const int l = tid & 63, w = tid >> 6;
    const int quad = l >> 4, l15 = l & 15;
    const int wm = w & 1, wn = w >> 1;

    for (int k0 = 0; k0 < K; k0 += BK) {
#pragma unroll
        for (int i = 0; i < 2; ++i) {
            int r16 = w * 32 + i * 16;
            const bf16* ga = A + (size_t)(m0 + r16 + (l >> 2)) * K + k0 + (l & 3) * 8;
            const bf16* gb = B + (size_t)(n0 + r16 + (l >> 2)) * K + k0 + (l & 3) * 8;
            llds16(ga, &sA[r16 * BK]);
            llds16(gb, &sB[r16 * BK]);
        }
        __syncthreads();

        bf16x8 af[4], bfr[4];
#pragma unroll
        for (int mi = 0; mi < 4; ++mi)
            af[mi] = *(const bf16x8*)&sA[(wm * 64 + mi * 16 + l15) * BK + quad * 8];
#pragma unroll
        for (int ni = 0; ni < 4; ++ni)
            bfr[ni] = *(const bf16x8*)&sB[(wn * 64 + ni * 16 + l15) * BK + quad * 8];
#pragma unroll
        for (int mi = 0; mi < 4; ++mi)
#pragma unroll
            for (int ni = 0; ni < 4; ++ni)
                acc[mi][ni] = MFMA32(af[mi], bfr[ni], acc[mi][ni]);
        __syncthreads();
    }
}

// ---- merged Q/K/V projections, one launch (768 blocks = 3/CU) ----
// z=0: Q (transposed, frag-major, carries softmax scale)
// z=1: K (transposed, frag-major)
// z=2: V (normal, frag-major V^T-compatible layout)
__global__ __launch_bounds__(256) void k_gemm_qkv(
    const bf16* __restrict__ qb, const bf16* __restrict__ kb, const bf16* __restrict__ vb,
    const bf16* __restrict__ wqb, const bf16* __restrict__ wkb, const bf16* __restrict__ wvb,
    const float* __restrict__ bq, const float* __restrict__ bk, const float* __restrict__ bv,
    bf16* __restrict__ Qf, bf16* __restrict__ Kf, bf16* __restrict__ Vf) {
    const int z = blockIdx.z;
    const bf16* A; const bf16* B; const float* bias;
    int m0, n0;
    if (z == 2) {
        A = vb; B = wvb; bias = bv;
        m0 = blockIdx.x * 128;    // s block (M = 4096)
        n0 = blockIdx.y * 128;    // feature block (N = 1024)
    } else {
        A = z ? wkb : wqb; B = z ? kb : qb; bias = z ? bk : bq;
        m0 = blockIdx.y * 128;    // feature block (M = 1024)
        n0 = blockIdx.x * 128;    // s block (N = 4096)
    }
    f32x4 acc[4][4] = {};
    gemm_main(A, B, m0, n0, acc);

    const int tid = threadIdx.x, l = tid & 63, w = tid >> 6;
    const int quad = l >> 4, l15 = l & 15;
    const int wm = w & 1, wn = w >> 1;

    if (z == 2) {
        // V epilogue: entry (bh, s32-block, d16-block); lane l15 = d, k(key) = quad*4+e
#pragma unroll
        for (int ni = 0; ni < 4; ++ni) {
            int col = n0 + wn * 64 + ni * 16 + l15;     // feature
            int h = col >> 6, nid = (col >> 4) & 3;
            float bias_v = bias[col];
#pragma unroll
            for (int mi2 = 0; mi2 < 4; mi2 += 2) {
                bf16x8 pack;
#pragma unroll
                for (int half = 0; half < 2; ++half)
#pragma unroll
                    for (int r = 0; r < 4; ++r)
                        pack[half * 4 + r] = (bf16)(acc[mi2 + half][ni][r] + bias_v);
                int row = m0 + wm * 64 + mi2 * 16;
                int b = row >> 11, sl = row & 2047;
                size_t entry = ((size_t)(b * NH + h) * 64 + (sl >> 5)) * 4 + nid;
                *(bf16x8*)(Vf + entry * 512 + (size_t)(quad * 16 + l15) * 8) = pack;
            }
        }
    } else {
        bf16* out = z ? Kf : Qf;
        const float scale = z ? 1.0f : 0.18033688f;   // Q carries 0.125*log2(e)
        float bias_rv[4][4];
#pragma unroll
        for (int mi = 0; mi < 4; ++mi)
#pragma unroll
            for (int r = 0; r < 4; ++r)
                bias_rv[mi][r] = bias[m0 + wm * 64 + mi * 16 + quad * 4 + r];
#pragma unroll
        for (int ni = 0; ni < 4; ++ni) {
            int col = n0 + wn * 64 + ni * 16 + l15;     // global s
            int b = col >> 11, s = col & 2047;
            int kb16 = s >> 4;
#pragma unroll
            for (int mi2 = 0; mi2 < 4; mi2 += 2) {
                bf16x8 pack;
#pragma unroll
                for (int half = 0; half < 2; ++half)
#pragma unroll
                    for (int r = 0; r < 4; ++r) {
                        float x = (acc[mi2 + half][ni][r] + bias_rv[mi2 + half][r]) * scale;
                        pack[half * 4 + r] = (bf16)x;
                    }
                int drow = m0 + wm * 64 + mi2 * 16;
                int h = (drow >> 6) & 15, p = (drow >> 5) & 1;
                size_t entry = ((size_t)((b * NH + h) * 128 + kb16)) * 2 + p;
                *(bf16x8*)(out + entry * 512 + (size_t)(quad * 16 + l15) * 8) = pack;
            }
        }
    }
}

// ---- output projection: 128(M)x64(N) tiles -> 512 blocks (2/CU) ----
__global__ __launch_bounds__(256) void k_gemm_out(
    const bf16* __restrict__ X, const bf16* __restrict__ wob,
    const float* __restrict__ bo, float* __restrict__ out) {
    constexpr int K = DM, BK = 32;
    const int m0 = blockIdx.y * 128, n0 = blockIdx.x * 64;
    __shared__ bf16 sA[128 * BK];
    __shared__ bf16 sB[64 * BK];
    const int tid = threadIdx.x;
    const int l = tid & 63, w = tid >> 6;
    const int quad = l >> 4, l15 = l & 15;
    const int wm = w & 1, wn = w >> 1;

    f32x4 acc[4][2] = {};
    for (int k0 = 0; k0 < K; k0 += BK) {
#pragma unroll
        for (int i = 0; i < 2; ++i) {
            int r16 = w * 32 + i * 16;
            const bf16* ga = X + (size_t)(m0 + r16 + (l >> 2)) * K + k0 + (l & 3) * 8;
            llds16(ga, &sA[r16 * BK]);
        }
        {
            int r16 = w * 16;
            const bf16* gb = wob + (size_t)(n0 + r16 + (l >> 2)) * K + k0 + (l & 3) * 8;
            llds16(gb, &sB[r16 * BK]);
        }
        __syncthreads();

        bf16x8 af[4], bfr[2];
#pragma unroll
        for (int mi = 0; mi < 4; ++mi)
            af[mi] = *(const bf16x8*)&sA[(wm * 64 + mi * 16 + l15) * BK + quad * 8];
#pragma unroll
        for (int ni = 0; ni < 2; ++ni)
            bfr[ni] = *(const bf16x8*)&sB[(wn * 32 + ni * 16 + l15) * BK + quad * 8];
#pragma unroll
        for (int mi = 0; mi < 4; ++mi)
#pragma unroll
            for (int ni = 0; ni < 2; ++ni)
                acc[mi][ni] = MFMA32(af[mi], bfr[ni], acc[mi][ni]);
        __syncthreads();
    }
#pragma unroll
    for (int mi = 0; mi < 4; ++mi)
#pragma unroll
        for (int ni = 0; ni < 2; ++ni) {
            int col = n0 + wn * 32 + ni * 16 + l15;
            float bias_v = bo[col];
            int rbase = m0 + wm * 64 + mi * 16 + quad * 4;
#pragma unroll
            for (int r = 0; r < 4; ++r)
                out[(size_t)(rbase + r) * DM + col] = acc[mi][ni][r] + bias_v;
        }
}

// ---------------- causal flash attention ----------------
// grid (bh=32, 32): qt = 31 - y (LPT: heavy tiles dispatch first); XCD = bh%8 pins K/V to L2.
// 2 waves/block, 32 Q rows/wave. S^T = K·Q^T (16x16x16); O^T = V^T·P^T -> softmax state,
// alpha rescale, and normalize all in-lane (col = query = l15). K double-buffered, V
// prefetched before QK^T: registers are free (occupancy is grid-limited at 2 waves/SIMD).
__global__ __launch_bounds__(128) void k_flash(const bf16* __restrict__ Qf,
                                               const bf16* __restrict__ Kf,
                                               const bf16* __restrict__ Vf,
                                               bf16* __restrict__ X) {
    const int bh = blockIdx.x;
    const int qt = 31 - blockIdx.y;          // LPT order
    const int b = bh >> 4, h = bh & 15;
    const int tid = threadIdx.x, w = tid >> 6, l = tid & 63;
    const int quad = l >> 4, l15 = l & 15;
    __shared__ bf16 xs[2][32 * 72];

    const bf16* kf = Kf + (size_t)bh * 128 * 1024;
    const bf16* vf = Vf + (size_t)bh * 64 * 4 * 512;
    const bf16* qfp = Qf + (size_t)bh * 128 * 1024;
    const int row0 = qt * 64 + w * 32;

    // persistent Q frags: [mt][p]
    HU q16[2][2];
#pragma unroll
    for (int mt = 0; mt < 2; ++mt)
#pragma unroll
        for (int p = 0; p < 2; ++p)
            q16[mt][p].v = *(const bf16x8*)(qfp + ((size_t)((row0 >> 4) + mt) * 2 + p) * 512 + (size_t)l * 8);

    float ms[2] = {-1e30f, -1e30f}, ls[2] = {0.f, 0.f};
    f32x4 of[2][4] = {};    // O^T: of[mt][dblk]; col=query(l15), row=quad*4+r = d

    // preload K(0)
    HU kl[4][2];
#pragma unroll
    for (int ni = 0; ni < 4; ++ni)
#pragma unroll
        for (int p = 0; p < 2; ++p)
            kl[ni][p].v = *(const bf16x8*)(kf + ((size_t)(0 * 4 + ni) * 2 + p) * 512 + (size_t)l * 8);

    for (int j = 0; j <= qt; ++j) {
        // ---- prefetch V(j): used after softmax (long slack) ----
        HU vl[2][4];
#pragma unroll
        for (int sp = 0; sp < 2; ++sp)
#pragma unroll
            for (int db = 0; db < 4; ++db)
                vl[sp][db].v = *(const bf16x8*)(vf + ((size_t)((j * 2 + sp) * 4 + db)) * 512 + (size_t)l * 8);
        // ---- prefetch K(j+1): used next iteration ----
        HU kn[4][2];
        if (j < qt) {
#pragma unroll
            for (int ni = 0; ni < 4; ++ni)
#pragma unroll
                for (int p = 0; p < 2; ++p)
                    kn[ni][p].v = *(const bf16x8*)(kf + ((size_t)((j + 1) * 4 + ni) * 2 + p) * 512 + (size_t)l * 8);
        }

        // ---- S^T = K·Q^T : sa[mt][ni]; col l15 = query, row quad*4+r = key ----
        f32x4 sa[2][4] = {};
#pragma unroll
        for (int kc = 0; kc < 4; ++kc)
#pragma unroll
            for (int ni = 0; ni < 4; ++ni)
#pragma unroll
                for (int mt = 0; mt < 2; ++mt)
                    sa[mt][ni] = MFMA1K(kl[ni][kc >> 1].h[kc & 1], q16[mt][kc >> 1].h[kc & 1],
                                        sa[mt][ni]);

        // ---- causal mask (diag tile only); scores already in log2 domain ----
        if (j == qt) {
#pragma unroll
            for (int mt = 0; mt < 2; ++mt)
#pragma unroll
                for (int ni = 0; ni < 4; ++ni)
#pragma unroll
                    for (int r = 0; r < 4; ++r) {
                        int n = j * 64 + ni * 16 + quad * 4 + r;
                        int m = row0 + mt * 16 + l15;
                        if (n > m) sa[mt][ni][r] = -1e30f;
                    }
        }

        // ---- online softmax: fully per-lane state (query = l15) ----
        s16x4 pf[2][4];
#pragma unroll
        for (int mt = 0; mt < 2; ++mt) {
            float mx = sa[mt][0][0];
#pragma unroll
            for (int ni = 0; ni < 4; ++ni)
#pragma unroll
                for (int r = 0; r < 4; ++r) mx = fmaxf(mx, sa[mt][ni][r]);
            mx = fmaxf(mx, __shfl_xor(mx, 16, 64));
            mx = fmaxf(mx, __shfl_xor(mx, 32, 64));
            float mnew = fmaxf(ms[mt], mx);
            float al = __builtin_amdgcn_exp2f(ms[mt] - mnew);
            ms[mt] = mnew;
            float sum = 0.f;
#pragma unroll
            for (int ni = 0; ni < 4; ++ni) {
                PU pu;
#pragma unroll
                for (int r = 0; r < 4; ++r) {
                    float e = __builtin_amdgcn_exp2f(sa[mt][ni][r] - mnew);
                    sum += e;
                    pu.b[r] = (bf16)e;
                }
                pf[mt][ni] = pu.s;
            }
            sum += __shfl_xor(sum, 16, 64);
            sum += __shfl_xor(sum, 32, 64);
            ls[mt] = ls[mt] * al + sum;
            // in-lane alpha rescale of O^T (col = query = this lane)
#pragma unroll
            for (int db = 0; db < 4; ++db)
#pragma unroll
                for (int r = 0; r < 4; ++r) of[mt][db][r] *= al;
        }

        // ---- O^T += V^T·P^T (A = V^T frag, B = P^T from regs) ----
#pragma unroll
        for (int sp = 0; sp < 2; ++sp)
#pragma unroll
            for (int db = 0; db < 4; ++db)
#pragma unroll
                for (int mt = 0; mt < 2; ++mt) {
                    of[mt][db] = MFMA1K(vl[sp][db].h[0], pf[mt][sp * 2 + 0], of[mt][db]);
                    of[mt][db] = MFMA1K(vl[sp][db].h[1], pf[mt][sp * 2 + 1], of[mt][db]);
                }

        if (j < qt) {
#pragma unroll
            for (int ni = 0; ni < 4; ++ni)
#pragma unroll
                for (int p = 0; p < 2; ++p)
                    kl[ni][p] = kn[ni][p];
        }
    }

    // ---- normalize (in-lane), repack via LDS, coalesced store ----
#pragma unroll
    for (int mt = 0; mt < 2; ++mt) {
        float rv = 1.f / ls[mt];
#pragma unroll
        for (int db = 0; db < 4; ++db) {
            bf16x4 pack;
#pragma unroll
            for (int r = 0; r < 4; ++r)
                pack[r] = (bf16)(of[mt][db][r] * rv);
            *(bf16x4*)&xs[w][(mt * 16 + l15) * 72 + db * 16 + quad * 4] = pack;
        }
    }
    // wave-private LDS; compiler inserts lgkmcnt waits
#pragma unroll
    for (int i = 0; i < 4; ++i) {
        int rowl = i * 8 + (l >> 3);
        bf16x8 vv = *(const bf16x8*)&xs[w][rowl * 72 + (l & 7) * 8];
        *(bf16x8*)(X + (size_t)(b * SEQ + row0 + rowl) * DM + h * 64 + (l & 7) * 8) = vv;
    }
}

// ---------------- launcher ----------------
extern "C" void kernel_launch(void* const* d_in, const int* in_sizes, int n_in,
                              void* d_out, int out_size, void* d_ws, size_t ws_size,
                              hipStream_t stream) {
    const float* q  = (const float*)d_in[0];
    const float* k  = (const float*)d_in[1];
    const float* v  = (const float*)d_in[2];
    // d_in[3] = mask: causal tril, handled analytically
    const float* wq = (const float*)d_in[4];
    const float* bq = (const float*)d_in[5];
    const float* wk = (const float*)d_in[6];
    const float* bk = (const float*)d_in[7];
    const float* wv = (const float*)d_in[8];
    const float* bv = (const float*)d_in[9];
    const float* wo = (const float*)d_in[10];
    const float* bo = (const float*)d_in[11];
    float* out = (float*)d_out;

    uint8_t* ws = (uint8_t*)d_ws;
    const size_t SZ_ACT = (size_t)MROWS * DM * sizeof(bf16);  // 8 MB
    const size_t SZ_W   = (size_t)DM * DM * sizeof(bf16);     // 2 MB
    bf16* qb  = (bf16*)(ws);
    bf16* kb  = (bf16*)(ws + SZ_ACT);
    bf16* vb  = (bf16*)(ws + 2 * SZ_ACT);
    bf16* wqb = (bf16*)(ws + 3 * SZ_ACT);
    bf16* wkb = (bf16*)(ws + 3 * SZ_ACT + SZ_W);
    bf16* wvb = (bf16*)(ws + 3 * SZ_ACT + 2 * SZ_W);
    bf16* wob = (bf16*)(ws + 3 * SZ_ACT + 3 * SZ_W);
    bf16* Qf  = (bf16*)(ws + 3 * SZ_ACT + 4 * SZ_W);
    bf16* Kf  = (bf16*)(ws + 4 * SZ_ACT + 4 * SZ_W);
    bf16* Vf  = (bf16*)(ws + 5 * SZ_ACT + 4 * SZ_W);
    bf16* X   = (bf16*)(ws + 6 * SZ_ACT + 4 * SZ_W);
    // total: 7*SZ_ACT + 4*SZ_W = 64 MB

    // 1) convert to bf16
    {
        long total_vec4 = 3L * MROWS * DM / 4 + 4L * DM * DM / 4;
        k_convert<<<dim3((unsigned)(total_vec4 / 256)), 256, 0, stream>>>(
            q, k, v, wq, wk, wv, wo, qb, kb, vb, wqb, wkb, wvb, wob);
    }
    // 2) merged Q/K/V projections (one launch, 768 blocks)
    k_gemm_qkv<<<dim3(32, 8, 3), 256, 0, stream>>>(
        qb, kb, vb, wqb, wkb, wvb, bq, bk, bv, Qf, Kf, Vf);
    // 3) causal flash attention
    k_flash<<<dim3(BATCH * NH, SEQ / 64), 128, 0, stream>>>(Qf, Kf, Vf, X);
    // 4) output projection -> fp32 (128x64 tiles, 512 blocks)
    k_gemm_out<<<dim3(DM / 64, MROWS / 128), 256, 0, stream>>>(X, wob, bo, out);
}

// Round 6
// 238.497 us; speedup vs baseline: 1.4428x; 1.0107x over previous
//
#include <hip/hip_runtime.h>
#include <hip/hip_bf16.h>
#include <cstdint>
#include <cstddef>

// ---- problem constants ----
#define BATCH 2
#define SEQ   2048
#define DM    1024
#define NH    16
#define DK    64
#define MROWS (BATCH*SEQ)   // 4096

typedef __bf16 bf16;
typedef float  f32x4  __attribute__((ext_vector_type(4)));
typedef bf16   bf16x8 __attribute__((ext_vector_type(8)));
typedef bf16   bf16x4 __attribute__((ext_vector_type(4)));

// verified (m89/m120): A[m=lane&15][k=(lane>>4)*8+j], B[n=lane&15][k=(lane>>4)*8+j],
// C/D: col(n)=lane&15, row(m)=(lane>>4)*4+reg
#define MFMA32(a, b, c) __builtin_amdgcn_mfma_f32_16x16x32_bf16(a, b, c, 0, 0, 0)

// async global->LDS, 16B per lane; LDS dest is wave-uniform base + lane*16
__device__ __forceinline__ void llds16(const void* gc, void* l) {
    void* g = (void*)gc;
    __builtin_amdgcn_global_load_lds(
        (__attribute__((address_space(1))) uint32_t*)g,
        (__attribute__((address_space(3))) uint32_t*)l,
        16, 0, 0);
}

// ---------------- fused fp32 -> bf16 convert (q,k,v + 4 weights) ----------------
__global__ __launch_bounds__(256) void k_convert(
    const float* __restrict__ q, const float* __restrict__ k, const float* __restrict__ v,
    const float* __restrict__ wq, const float* __restrict__ wk, const float* __restrict__ wv,
    const float* __restrict__ wo,
    bf16* __restrict__ qb, bf16* __restrict__ kb, bf16* __restrict__ vb,
    bf16* __restrict__ wqb, bf16* __restrict__ wkb, bf16* __restrict__ wvb,
    bf16* __restrict__ wob) {
    long t = (long)blockIdx.x * blockDim.x + threadIdx.x;   // one float4 per thread
    const long NQ = (long)MROWS * DM / 4;
    const long NW = (long)DM * DM / 4;
    const float* src; bf16* dst; long off;
    if (t < NQ)            { src = q;  dst = qb;  off = t; }
    else if (t < 2*NQ)     { src = k;  dst = kb;  off = t - NQ; }
    else if (t < 3*NQ)     { src = v;  dst = vb;  off = t - 2*NQ; }
    else {
        long u = t - 3*NQ;
        if (u < NW)        { src = wq; dst = wqb; off = u; }
        else if (u < 2*NW) { src = wk; dst = wkb; off = u - NW; }
        else if (u < 3*NW) { src = wv; dst = wvb; off = u - 2*NW; }
        else               { src = wo; dst = wob; off = u - 3*NW; }
    }
    f32x4 x = *(const f32x4*)(src + off * 4);
    bf16x4 y;
    y[0] = (bf16)x[0]; y[1] = (bf16)x[1]; y[2] = (bf16)x[2]; y[3] = (bf16)x[3];
    *(bf16x4*)(dst + off * 4) = y;
}

// ---------------- m97-style GEMM mainloop: acc = A[M,K] * B[N,K]^T ----------------
__device__ __forceinline__ void gemm_main(const bf16* __restrict__ A, const bf16* __restrict__ B,
                                          int m0, int n0, f32x4 acc[4][4]) {
    constexpr int K = DM, BK = 32;
    __shared__ bf16 sA[128 * BK];
    __shared__ bf16 sB[128 * BK];
    const int tid = threadIdx.x;
    const int l = tid & 63, w = tid >> 6;
    const int quad = l >> 4, l15 = l & 15;
    const int wm = w & 1, wn = w >> 1;

    for (int k0 = 0; k0 < K; k0 += BK) {
#pragma unroll
        for (int i = 0; i < 2; ++i) {
            int r16 = w * 32 + i * 16;
            const bf16* ga = A + (size_t)(m0 + r16 + (l >> 2)) * K + k0 + (l & 3) * 8;
            const bf16* gb = B + (size_t)(n0 + r16 + (l >> 2)) * K + k0 + (l & 3) * 8;
            llds16(ga, &sA[r16 * BK]);
            llds16(gb, &sB[r16 * BK]);
        }
        __syncthreads();

        bf16x8 af[4], bfr[4];
#pragma unroll
        for (int mi = 0; mi < 4; ++mi)
            af[mi] = *(const bf16x8*)&sA[(wm * 64 + mi * 16 + l15) * BK + quad * 8];
#pragma unroll
        for (int ni = 0; ni < 4; ++ni)
            bfr[ni] = *(const bf16x8*)&sB[(wn * 64 + ni * 16 + l15) * BK + quad * 8];
#pragma unroll
        for (int mi = 0; mi < 4; ++mi)
#pragma unroll
            for (int ni = 0; ni < 4; ++ni)
                acc[mi][ni] = MFMA32(af[mi], bfr[ni], acc[mi][ni]);
        __syncthreads();
    }
}

// ---- merged Q/K/V projections, frag-major epilogues for the 16x16x32 flash ----
// Qf/Kf entry (bh, s16 = s>>4, chunk = d>>5): 512 elems (1KB); lane l, elem e holds
//   [s-in-16 = l&15][d-in-32 = (l>>4)*8 + e]   (= MFMA A/B-operand order)
// Vf entry (bh, kc = s>>5, dtile = d>>4): lane l, elem e holds
//   [d-in-16 = l&15][key-in-32 = (l>>4)*8 + e]
__global__ __launch_bounds__(256) void k_gemm_qkv(
    const bf16* __restrict__ qb, const bf16* __restrict__ kb, const bf16* __restrict__ vb,
    const bf16* __restrict__ wqb, const bf16* __restrict__ wkb, const bf16* __restrict__ wvb,
    const float* __restrict__ bq, const float* __restrict__ bk, const float* __restrict__ bv,
    bf16* __restrict__ Qf, bf16* __restrict__ Kf, bf16* __restrict__ Vf) {
    const int z = blockIdx.z;
    const bf16* A; const bf16* B; const float* bias;
    int m0, n0;
    if (z == 2) {
        A = vb; B = wvb; bias = bv;
        m0 = blockIdx.x * 128;    // s block (M = 4096)
        n0 = blockIdx.y * 128;    // feature block (N = 1024)
    } else {
        A = z ? wkb : wqb; B = z ? kb : qb; bias = z ? bk : bq;
        m0 = blockIdx.y * 128;    // feature block (M = 1024)
        n0 = blockIdx.x * 128;    // s block (N = 4096)
    }
    f32x4 acc[4][4] = {};
    gemm_main(A, B, m0, n0, acc);

    const int tid = threadIdx.x, l = tid & 63, w = tid >> 6;
    const int quad = l >> 4, l15 = l & 15;
    const int wm = w & 1, wn = w >> 1;

    if (z == 2) {
        // V epilogue: acc element = V[s = m0+wm*64+mi*16+quad*4+r][d = n0+wn*64+ni*16+l15]
#pragma unroll
        for (int ni = 0; ni < 4; ++ni) {
            int dcol = n0 + wn * 64 + ni * 16 + l15;
            int hh2 = dcol >> 6;                 // head
            int dtile = (dcol >> 4) & 3;         // (d&63)>>4
            float bias_v = bias[dcol];
#pragma unroll
            for (int mi = 0; mi < 4; ++mi) {
                int srow = m0 + wm * 64 + mi * 16;
                int bb = srow >> 11, sl = srow & 2047;
                int kc = sl >> 5;
                int qp = 2 * (mi & 1) + (quad >> 1);   // (key32)>>3
                bf16x4 pack;
#pragma unroll
                for (int r = 0; r < 4; ++r)
                    pack[r] = (bf16)(acc[mi][ni][r] + bias_v);
                size_t entry = ((size_t)(bb * NH + hh2) * 64 + kc) * 4 + dtile;
                *(bf16x4*)(Vf + entry * 512 + (size_t)(qp * 16 + l15) * 8 + (quad & 1) * 4) = pack;
            }
        }
    } else {
        // Q/K epilogue: acc element = D[feature = m0+wm*64+mi*16+quad*4+r][s = n0+wn*64+ni*16+l15]
        bf16* out = z ? Kf : Qf;
        const float scale = z ? 1.0f : 0.18033688f;   // Q carries 0.125 * log2(e)
        float bias_rv[4][4];
#pragma unroll
        for (int mi = 0; mi < 4; ++mi)
#pragma unroll
            for (int r = 0; r < 4; ++r)
                bias_rv[mi][r] = bias[m0 + wm * 64 + mi * 16 + quad * 4 + r];
#pragma unroll
        for (int ni = 0; ni < 4; ++ni) {
            int scol = n0 + wn * 64 + ni * 16 + l15;
            int bb = scol >> 11, s = scol & 2047;
            int s16 = s >> 4;
#pragma unroll
            for (int mi = 0; mi < 4; ++mi) {
                int drow = m0 + wm * 64 + mi * 16;
                int hh2 = (drow >> 6) & 15;
                int chunk = (drow & 63) >> 5;
                int qp = 2 * (mi & 1) + (quad >> 1);   // (d32)>>3
                bf16x4 pack;
#pragma unroll
                for (int r = 0; r < 4; ++r)
                    pack[r] = (bf16)((acc[mi][ni][r] + bias_rv[mi][r]) * scale);
                size_t entry = ((size_t)(bb * NH + hh2) * 128 + s16) * 2 + chunk;
                *(bf16x4*)(out + entry * 512 + (size_t)(qp * 16 + l15) * 8 + (quad & 1) * 4) = pack;
            }
        }
    }
}

// ---- output projection: 128(M)x64(N) tiles -> 512 blocks (2/CU) ----
__global__ __launch_bounds__(256) void k_gemm_out(
    const bf16* __restrict__ X, const bf16* __restrict__ wob,
    const float* __restrict__ bo, float* __restrict__ out) {
    constexpr int K = DM, BK = 32;
    const int m0 = blockIdx.y * 128, n0 = blockIdx.x * 64;
    __shared__ bf16 sA[128 * BK];
    __shared__ bf16 sB[64 * BK];
    const int tid = threadIdx.x;
    const int l = tid & 63, w = tid >> 6;
    const int quad = l >> 4, l15 = l & 15;
    const int wm = w & 1, wn = w >> 1;

    f32x4 acc[4][2] = {};
    for (int k0 = 0; k0 < K; k0 += BK) {
#pragma unroll
        for (int i = 0; i < 2; ++i) {
            int r16 = w * 32 + i * 16;
            const bf16* ga = X + (size_t)(m0 + r16 + (l >> 2)) * K + k0 + (l & 3) * 8;
            llds16(ga, &sA[r16 * BK]);
        }
        {
            int r16 = w * 16;
            const bf16* gb = wob + (size_t)(n0 + r16 + (l >> 2)) * K + k0 + (l & 3) * 8;
            llds16(gb, &sB[r16 * BK]);
        }
        __syncthreads();

        bf16x8 af[4], bfr[2];
#pragma unroll
        for (int mi = 0; mi < 4; ++mi)
            af[mi] = *(const bf16x8*)&sA[(wm * 64 + mi * 16 + l15) * BK + quad * 8];
#pragma unroll
        for (int ni = 0; ni < 2; ++ni)
            bfr[ni] = *(const bf16x8*)&sB[(wn * 32 + ni * 16 + l15) * BK + quad * 8];
#pragma unroll
        for (int mi = 0; mi < 4; ++mi)
#pragma unroll
            for (int ni = 0; ni < 2; ++ni)
                acc[mi][ni] = MFMA32(af[mi], bfr[ni], acc[mi][ni]);
        __syncthreads();
    }
#pragma unroll
    for (int mi = 0; mi < 4; ++mi)
#pragma unroll
        for (int ni = 0; ni < 2; ++ni) {
            int col = n0 + wn * 32 + ni * 16 + l15;
            float bias_v = bo[col];
            int rbase = m0 + wm * 64 + mi * 16 + quad * 4;
#pragma unroll
            for (int r = 0; r < 4; ++r)
                out[(size_t)(rbase + r) * DM + col] = acc[mi][ni][r] + bias_v;
        }
}

// ---------------- causal flash attention, native 16x16x32 MFMA only ----------------
// grid (bh=32, 64): qt32 = 63-((y+bh)&63) (LPT-ish balance); XCD = id&7 = bh&7 pins K/V.
// Block = 2 independent waves; wave owns 16 queries (qt16 = qt32*2 + w).
// S^T = K·Q^T: C col = query = l15 (in-lane softmax state, fixed-m exp2 domain).
// P via wave-private LDS (verified transform); O^T = V^T·P^T keeps query in-lane.
__global__ __launch_bounds__(128, 3) void k_flash(const bf16* __restrict__ Qf,
                                                  const bf16* __restrict__ Kf,
                                                  const bf16* __restrict__ Vf,
                                                  bf16* __restrict__ X) {
    const int bh = blockIdx.x;
    const int qt32 = 63 - ((blockIdx.y + bh) & 63);
    const int b = bh >> 4, h = bh & 15;
    const int tid = threadIdx.x, w = tid >> 6, l = tid & 63;
    const int quad = l >> 4, l15 = l & 15;
    __shared__ bf16 P[2][16 * 72];   // per-wave P^T scratch: [query][key], pitch 72
    bf16* Pw = P[w];

    const int qt16 = qt32 * 2 + w;
    const bf16* qfp = Qf + (size_t)bh * 128 * 1024;
    const bf16* kfp = Kf + (size_t)bh * 128 * 1024;
    const bf16* vfp = Vf + (size_t)bh * 64 * 4 * 512;

    // persistent Q B-frags: [chunk] (d 0..31, 32..63)
    bf16x8 qf[2];
#pragma unroll
    for (int c = 0; c < 2; ++c)
        qf[c] = *(const bf16x8*)(qfp + ((size_t)qt16 * 2 + c) * 512 + (size_t)l * 8);

    f32x4 o[4] = {};            // O^T: row = d-in-16 (dtile), col = query = l15
    float lp = 0.f;             // per-lane partial softmax denom (this quad's keys)
    const int jmax = qt16 >> 2; // 64-key tiles
    const int qglob = qt16 * 16 + l15;

    for (int j = 0; j <= jmax; ++j) {
        // ---- K frags (8 coalesced 16B loads) ----
        bf16x8 kl[4][2];
#pragma unroll
        for (int ni = 0; ni < 4; ++ni)
#pragma unroll
            for (int c = 0; c < 2; ++c)
                kl[ni][c] = *(const bf16x8*)(kfp + ((size_t)(j * 4 + ni) * 2 + c) * 512 + (size_t)l * 8);

        // ---- S^T = K·Q^T per 16-key subtile ----
        f32x4 st[4];
#pragma unroll
        for (int ni = 0; ni < 4; ++ni) {
            f32x4 zz = {};
            zz = MFMA32(kl[ni][0], qf[0], zz);
            st[ni] = MFMA32(kl[ni][1], qf[1], zz);
        }

        // ---- V frags (issued early; consumed after softmax) ----
        bf16x8 vl[2][4];
#pragma unroll
        for (int c = 0; c < 2; ++c)
#pragma unroll
            for (int dt = 0; dt < 4; ++dt)
                vl[c][dt] = *(const bf16x8*)(vfp + ((size_t)(j * 2 + c) * 4 + dt) * 512 + (size_t)l * 8);

        // ---- fixed-m softmax (scores already in log2 domain) + P -> LDS ----
        const bool diag = (j == jmax);
#pragma unroll
        for (int ni = 0; ni < 4; ++ni) {
            bf16x4 ev;
#pragma unroll
            for (int r = 0; r < 4; ++r) {
                float s = st[ni][r];
                if (diag) {
                    int key = j * 64 + ni * 16 + quad * 4 + r;
                    if (key > qglob) s = -1e30f;
                }
                float e = __builtin_amdgcn_exp2f(s);
                lp += e;
                ev[r] = (bf16)e;
            }
            *(bf16x4*)&Pw[l15 * 72 + ni * 16 + quad * 4] = ev;
        }

        // ---- O^T += V^T·P^T per 32-key chunk ----
#pragma unroll
        for (int c = 0; c < 2; ++c) {
            bf16x8 pb = *(const bf16x8*)&Pw[l15 * 72 + c * 32 + quad * 8];
#pragma unroll
            for (int dt = 0; dt < 4; ++dt)
                o[dt] = MFMA32(vl[c][dt], pb, o[dt]);
        }
    }

    // ---- reduce denom across quads (queries are per-lane) ----
    lp += __shfl_xor(lp, 16, 64);
    lp += __shfl_xor(lp, 32, 64);
    float rv = 1.f / lp;

    // ---- normalize, repack via wave-private LDS, coalesced store ----
#pragma unroll
    for (int dt = 0; dt < 4; ++dt) {
        bf16x4 pk;
#pragma unroll
        for (int r = 0; r < 4; ++r)
            pk[r] = (bf16)(o[dt][r] * rv);
        *(bf16x4*)&Pw[l15 * 72 + dt * 16 + quad * 4] = pk;
    }
#pragma unroll
    for (int i = 0; i < 2; ++i) {
        int row = i * 8 + (l >> 3);
        bf16x8 vv = *(const bf16x8*)&Pw[row * 72 + (l & 7) * 8];
        *(bf16x8*)(X + (size_t)(b * SEQ + qt16 * 16 + row) * DM + h * 64 + (l & 7) * 8) = vv;
    }
}

// ---------------- launcher ----------------
extern "C" void kernel_launch(void* const* d_in, const int* in_sizes, int n_in,
                              void* d_out, int out_size, void* d_ws, size_t ws_size,
                              hipStream_t stream) {
    const float* q  = (const float*)d_in[0];
    const float* k  = (const float*)d_in[1];
    const float* v  = (const float*)d_in[2];
    // d_in[3] = mask: causal tril, handled analytically
    const float* wq = (const float*)d_in[4];
    const float* bq = (const float*)d_in[5];
    const float* wk = (const float*)d_in[6];
    const float* bk = (const float*)d_in[7];
    const float* wv = (const float*)d_in[8];
    const float* bv = (const float*)d_in[9];
    const float* wo = (const float*)d_in[10];
    const float* bo = (const float*)d_in[11];
    float* out = (float*)d_out;

    uint8_t* ws = (uint8_t*)d_ws;
    const size_t SZ_ACT = (size_t)MROWS * DM * sizeof(bf16);  // 8 MB
    const size_t SZ_W   = (size_t)DM * DM * sizeof(bf16);     // 2 MB
    bf16* qb  = (bf16*)(ws);
    bf16* kb  = (bf16*)(ws + SZ_ACT);
    bf16* vb  = (bf16*)(ws + 2 * SZ_ACT);
    bf16* wqb = (bf16*)(ws + 3 * SZ_ACT);
    bf16* wkb = (bf16*)(ws + 3 * SZ_ACT + SZ_W);
    bf16* wvb = (bf16*)(ws + 3 * SZ_ACT + 2 * SZ_W);
    bf16* wob = (bf16*)(ws + 3 * SZ_ACT + 3 * SZ_W);
    bf16* Qf  = (bf16*)(ws + 3 * SZ_ACT + 4 * SZ_W);
    bf16* Kf  = (bf16*)(ws + 4 * SZ_ACT + 4 * SZ_W);
    bf16* Vf  = (bf16*)(ws + 5 * SZ_ACT + 4 * SZ_W);
    bf16* X   = (bf16*)(ws + 6 * SZ_ACT + 4 * SZ_W);
    // total: 7*SZ_ACT + 4*SZ_W = 64 MB

    // 1) convert to bf16
    {
        long total_vec4 = 3L * MROWS * DM / 4 + 4L * DM * DM / 4;
        k_convert<<<dim3((unsigned)(total_vec4 / 256)), 256, 0, stream>>>(
            q, k, v, wq, wk, wv, wo, qb, kb, vb, wqb, wkb, wvb, wob);
    }
    // 2) merged Q/K/V projections (frag-major epilogues)
    k_gemm_qkv<<<dim3(32, 8, 3), 256, 0, stream>>>(
        qb, kb, vb, wqb, wkb, wvb, bq, bk, bv, Qf, Kf, Vf);
    // 3) causal flash attention (16-query waves, 16x16x32 MFMA)
    k_flash<<<dim3(BATCH * NH, SEQ / 32), 128, 0, stream>>>(Qf, Kf, Vf, X);
    // 4) output projection -> fp32 (128x64 tiles, 512 blocks)
    k_gemm_out<<<dim3(DM / 64, MROWS / 128), 256, 0, stream>>>(X, wob, bo, out);
}